// Round 7
// baseline (2515.685 us; speedup 1.0000x reference)
//
#include <hip/hip_runtime.h>
#include <hip/hip_bf16.h>

#define NN 50000
#define NE 200000
#define HEADS 4
#define EPSV 1e-5f
#define NEGS 0.01f

using f32x4 = __attribute__((ext_vector_type(4))) float;
using s16x8 = __attribute__((ext_vector_type(8))) short;
using bf16x8 = __attribute__((ext_vector_type(8))) __bf16;

__device__ __forceinline__ short f2bf(float f) {
    union { float f; unsigned u; } v; v.f = f;
    unsigned r = v.u + 0x7FFFu + ((v.u >> 16) & 1u);
    return (short)(r >> 16);
}
__device__ __forceinline__ float bf2f(short s) {
    union { unsigned u; float f; } v; v.u = ((unsigned)(unsigned short)s) << 16;
    return v.f;
}
__device__ __forceinline__ f32x4 mfma16(s16x8 a, s16x8 b, f32x4 c) {
    return __builtin_amdgcn_mfma_f32_16x16x32_bf16(
        __builtin_bit_cast(bf16x8, a), __builtin_bit_cast(bf16x8, b), c, 0, 0, 0);
}
__device__ __forceinline__ void gld16(const void* g, void* l) {
    __builtin_amdgcn_global_load_lds(
        (const __attribute__((address_space(1))) void*)g,
        (__attribute__((address_space(3))) void*)l, 16, 0, 0);
}
// DMA one 32KB chunk (16384 shorts) image -> LDS, all 512 threads (4 ops each)
__device__ __forceinline__ void dma_chunk(const short* src, char* dst, int w, int tid) {
    #pragma unroll
    for (int op = 0; op < 4; ++op)
        gld16(src + op * 4096 + tid * 8, dst + op * 8192 + w * 1024);
}

// ---------------- weight prep (unchanged from R6-verified) ----------------
__global__ void prep_weights(const float* __restrict__ Kv2v, const float* __restrict__ Vv2v,
                             const float* __restrict__ inpW,
                             const float* __restrict__ Ke2v, const float* __restrict__ Ve2v,
                             const float* __restrict__ luW, const float* __restrict__ msgW,
                             const float* __restrict__ catW,
                             short* __restrict__ nodeW_t, short* __restrict__ imgW)
{
    int i = blockIdx.x * 256 + threadIdx.x;
    if (i < 147456) {                       // nodeW_t [1152][128]
        int j = i >> 7, k = i & 127;
        float v;
        if (j < 512)       v = Kv2v[(j >> 7) * 16384 + k * 128 + (j & 127)];
        else if (j < 1024) v = Vv2v[((j - 512) >> 7) * 16384 + k * 128 + (j & 127)];
        else               v = inpW[k * 128 + (j - 1024)];
        nodeW_t[i] = f2bf(v);
        return;
    }
    i -= 147456;
    if (i >= 589824) return;
    int h = i / 147456;
    int r = i % 147456;
    short* img = imgW + h * 147456;
    if (r < 16384) {                        // KW (K=128)
        int colc = r >> 7, k = r & 127;
        img[(colc * 128 + k) ^ ((colc & 7) << 3)] = f2bf(Ke2v[h * 16384 + k * 128 + colc]);
    } else if (r < 32768) {                 // VW (K=128)
        int e = r - 16384; int colc = e >> 7, k = e & 127;
        img[16384 + ((colc * 128 + k) ^ ((colc & 7) << 3))] = f2bf(Ve2v[h * 16384 + k * 128 + colc]);
    } else if (r < 98304) {                 // LU (K=256, 4 chunks of 64 cols)
        int e = r - 32768; int c = e >> 14, ec = e & 16383;
        int colc = ec >> 8, k = ec & 255; int col = c * 64 + colc;
        img[32768 + c * 16384 + ((colc * 256 + k) ^ ((colc & 7) << 3))] =
            f2bf(luW[h * 65536 + k * 256 + col]);
    } else if (r < 131072) {                // MSG (K=256, 2 chunks of 64 cols)
        int e = r - 98304; int c = e >> 14, ec = e & 16383;
        int colc = ec >> 8, k = ec & 255; int col = c * 64 + colc;
        img[98304 + c * 16384 + ((colc * 256 + k) ^ ((colc & 7) << 3))] =
            f2bf(msgW[h * 32768 + k * 128 + col]);
    } else {                                // CAT (K=128)
        int e = r - 131072; int colc = e >> 7, k = e & 127;
        img[131072 + ((colc * 128 + k) ^ ((colc & 7) << 3))] =
            f2bf(catW[(h * 128 + k) * 128 + colc]);
    }
}

// ---------------- node projections (unchanged, verified) ----------------
__global__ __launch_bounds__(256, 2)
void node_proj(const float* __restrict__ x, const short* __restrict__ nodeW_t,
               short* __restrict__ Kv_all, short* __restrict__ Vv_all,
               float* __restrict__ resid)
{
    __shared__ alignas(16) short xt[64 * 128];
    const int tid = threadIdx.x;
    const int row0 = blockIdx.x * 64;
    #pragma unroll
    for (int it = 0; it < 8; ++it) {
        int idx4 = it * 256 + tid;
        int r = idx4 >> 5;
        int c = (idx4 & 31) * 4;
        float4 v = {0.f, 0.f, 0.f, 0.f};
        if (row0 + r < NN) v = *(const float4*)(x + (size_t)(row0 + r) * 128 + c);
        short4 sw; sw.x = f2bf(v.x); sw.y = f2bf(v.y); sw.z = f2bf(v.z); sw.w = f2bf(v.w);
        int byte = (r * 256 + c * 2) ^ ((r & 7) << 4);
        *(short4*)((char*)xt + byte) = sw;
    }
    __syncthreads();
    const int lane = tid & 63, w = tid >> 6;
    const int l15 = lane & 15, lg = lane >> 4;
    const int rloc = w * 16 + l15;
    s16x8 a[4];
    #pragma unroll
    for (int ks = 0; ks < 4; ++ks) {
        int byte = (rloc * 256 + (ks * 32 + lg * 8) * 2) ^ ((rloc & 7) << 4);
        a[ks] = *(const s16x8*)((const char*)xt + byte);
    }
    const int rowC = row0 + w * 16 + lg * 4;
    for (int nc = 0; nc < 18; ++nc) {
        f32x4 acc[4];
        s16x8 b[16];
        #pragma unroll
        for (int q = 0; q < 4; ++q) {
            acc[q] = (f32x4){0.f, 0.f, 0.f, 0.f};
            int j = (nc * 4 + q) * 16 + l15;
            #pragma unroll
            for (int ks = 0; ks < 4; ++ks)
                b[q * 4 + ks] = *(const s16x8*)(nodeW_t + j * 128 + ks * 32 + lg * 8);
        }
        #pragma unroll
        for (int q = 0; q < 4; ++q)
            #pragma unroll
            for (int ks = 0; ks < 4; ++ks)
                acc[q] = mfma16(a[ks], b[q * 4 + ks], acc[q]);
        #pragma unroll
        for (int q = 0; q < 4; ++q) {
            int j = (nc * 4 + q) * 16 + l15;
            #pragma unroll
            for (int r = 0; r < 4; ++r) {
                int row = rowC + r;
                if (row >= NN) continue;
                if (j < 512)       Kv_all[(size_t)row * 512 + j] = f2bf(acc[q][r]);
                else if (j < 1024) Vv_all[(size_t)row * 512 + (j - 512)] = f2bf(acc[q][r]);
                else               resid[(size_t)row * 128 + (j - 1024)] = acc[q][r];
            }
        }
    }
}

// ---------------- fused edge pipeline: 8 waves, 128 edges/block, dbuf DMA ----------------
// dynamic LDS 163840: wbuf0 @0 (32K), wbuf1 @32768 (32K),
// per-wave scratch @65536 + w*12288: q@0 [16][128], k1@4096, VE/m2@8192 [16][128],
// m1g@0 [16][256] (overlays q/k1)
#define B128(buf, ct, ks) \
    (*(const s16x8*)((const short*)(buf) + (((((ct) * 16 + l15) * 128) + (ks) * 32 + lg * 8) ^ ((l15 & 7) << 3))))
#define B256(buf, ct, ks) \
    (*(const s16x8*)((const short*)(buf) + (((((ct) * 16 + l15) * 256) + (ks) * 32 + lg * 8) ^ ((l15 & 7) << 3))))
#define CB() do { __syncthreads(); char* _t = bA; bA = bB; bB = _t; } while (0)
#define PRIO1() __builtin_amdgcn_s_setprio(1)
#define PRIO0() __builtin_amdgcn_s_setprio(0)

__global__ __launch_bounds__(512, 2)
void edge_kernel(const float* __restrict__ ef, const int* __restrict__ eidx,
                 const short* __restrict__ Kv_all, const short* __restrict__ Vv_all,
                 const short* __restrict__ imgW,
                 const float* __restrict__ lu_b, const float* __restrict__ ln1_g,
                 const float* __restrict__ ln1_b, const float* __restrict__ msg_b,
                 const float* __restrict__ ln2_g, const float* __restrict__ ln2_b,
                 float* __restrict__ out1)
{
    extern __shared__ char lds[];
    char* bA = lds;
    char* bB = lds + 32768;
    const int tid = threadIdx.x;
    const int lane = tid & 63, w = tid >> 6;
    const int l15 = lane & 15, lg = lane >> 4;
    const int e0 = blockIdx.x * 128 + w * 16;
    const int rb = lg * 4;
    char* myscr = lds + 65536 + w * 12288;
    const float scale = 0.0625f;   // 1/sqrt(2*OUT)

    // prologue: DMA KW(h=0) into bB; ef A-fragments; indices (clamped for tail)
    dma_chunk(imgW, bB, w, tid);
    const int eA = min(e0 + l15, NE - 1);
    const float* efr = ef + (size_t)eA * 128 + lg * 8;
    s16x8 aef[4];
    #pragma unroll
    for (int ks = 0; ks < 4; ++ks) {
        float4 v0 = *(const float4*)(efr + ks * 32);
        float4 v1 = *(const float4*)(efr + ks * 32 + 4);
        s16x8 t;
        t[0] = f2bf(v0.x); t[1] = f2bf(v0.y); t[2] = f2bf(v0.z); t[3] = f2bf(v0.w);
        t[4] = f2bf(v1.x); t[5] = f2bf(v1.y); t[6] = f2bf(v1.z); t[7] = f2bf(v1.w);
        aef[ks] = t;
    }
    const int srcA = eidx[eA];
    int dstC[4], validC[4];
    #pragma unroll
    for (int r = 0; r < 4; ++r) {
        int e = e0 + rb + r;
        validC[r] = (e < NE);
        dstC[r] = eidx[NE + min(e, NE - 1)];
    }
    const int gRow = lane >> 2;            // 0..15
    const int gChunk = lane & 3;           // 0..3
    const int eG = min(e0 + gRow, NE - 1);
    const int dstG = eidx[NE + eG];
    const int srcG = eidx[eG];

    f32x4 outc[8];
    #pragma unroll
    for (int nt = 0; nt < 8; ++nt) outc[nt] = (f32x4){0.f, 0.f, 0.f, 0.f};
    CB();   // KW0 ready in bA

    for (int h = 0; h < HEADS; ++h) {
        const short* hb = imgW + h * 147456;
        // q/k1 gathers (latency hidden under step 1)
        s16x8 qv[4], kv[4];
        #pragma unroll
        for (int j = 0; j < 4; ++j) {
            qv[j] = *(const s16x8*)(Kv_all + (size_t)dstG * 512 + h * 128 + gChunk * 32 + j * 8);
            kv[j] = *(const s16x8*)(Kv_all + (size_t)srcG * 512 + h * 128 + gChunk * 32 + j * 8);
        }

        // ---- step 1: DMA VW; accK = ef@KW (bA) ----
        dma_chunk(hb + 16384, bB, w, tid);
        f32x4 accK[8];
        #pragma unroll
        for (int nt = 0; nt < 8; ++nt) accK[nt] = (f32x4){0, 0, 0, 0};
        PRIO1();
        #pragma unroll
        for (int ks = 0; ks < 4; ++ks)
            #pragma unroll
            for (int ct = 0; ct < 8; ++ct)
                accK[ct] = mfma16(aef[ks], B128(bA, ct, ks), accK[ct]);
        PRIO0();
        #pragma unroll
        for (int j = 0; j < 4; ++j) {       // q/k1 -> scratch
            int byte = gRow * 256 + ((((gChunk * 4 + j) * 16)) ^ ((gRow & 7) << 4));
            *(s16x8*)(myscr + byte) = qv[j];
            *(s16x8*)(myscr + 4096 + byte) = kv[j];
        }
        CB();

        // ---- step 2: DMA LU0; accV = ef@VW (bA); VE->scratch; LN1+gate; vvr ----
        dma_chunk(hb + 32768, bB, w, tid);
        f32x4 accV[8];
        #pragma unroll
        for (int nt = 0; nt < 8; ++nt) accV[nt] = (f32x4){0, 0, 0, 0};
        PRIO1();
        #pragma unroll
        for (int ks = 0; ks < 4; ++ks)
            #pragma unroll
            for (int ct = 0; ct < 8; ++ct)
                accV[ct] = mfma16(aef[ks], B128(bA, ct, ks), accV[ct]);
        PRIO0();
        #pragma unroll
        for (int nt = 0; nt < 8; ++nt) {    // VE -> scratch @8192 [16][128]
            int c = nt * 16 + l15;
            #pragma unroll
            for (int r = 0; r < 4; ++r) {
                int row = rb + r;
                int byte = 8192 + ((row * 256 + c * 2) ^ ((row & 7) << 4));
                *(short*)(myscr + byte) = f2bf(accV[nt][r]);
            }
        }
        s16x8 vvr[4];
        #pragma unroll
        for (int ks = 0; ks < 4; ++ks)
            vvr[ks] = *(const s16x8*)(Vv_all + (size_t)srcA * 512 + h * 128 + ks * 32 + lg * 8);
        unsigned gpk[16][2];
        #pragma unroll
        for (int r = 0; r < 4; ++r) {       // LN1 + sigmoid gate (verified)
            const int i = rb + r;
            const int swz = (i & 7) << 4;
            float al[16];
            float s = 0.f, s2 = 0.f;
            #pragma unroll
            for (int nt = 0; nt < 8; ++nt) {
                int off = (i * 256 + nt * 32 + l15 * 2) ^ swz;
                float q  = bf2f(*(const short*)(myscr + off));
                float k1 = bf2f(*(const short*)(myscr + 4096 + off));
                float alo = q * k1 * scale;
                float ahi = q * accK[nt][r] * scale;
                al[nt] = alo; al[nt + 8] = ahi;
                s += alo + ahi; s2 += alo * alo + ahi * ahi;
            }
            #pragma unroll
            for (int m = 1; m < 16; m <<= 1) { s += __shfl_xor(s, m); s2 += __shfl_xor(s2, m); }
            float mean = s * (1.f / 256.f);
            float var  = s2 * (1.f / 256.f) - mean * mean;
            float rstd = rsqrtf(var + EPSV);
            #pragma unroll
            for (int i2 = 0; i2 < 16; ++i2) {
                int c = i2 * 16 + l15;
                float z = (al[i2] - mean) * rstd * ln1_g[h * 256 + c] + ln1_b[h * 256 + c];
                float g = 1.f / (1.f + __expf(-z));
                unsigned gb = (unsigned)(unsigned short)f2bf(g);
                if ((r & 1) == 0) gpk[i2][r >> 1] = gb;
                else              gpk[i2][r >> 1] |= gb << 16;
            }
        }
        CB();

        // ---- steps 3-6: stage C, luW chunks c=0..3 (64 cols each) ----
        f32x4 m1[16];
        #pragma unroll
        for (int nt = 0; nt < 16; ++nt) m1[nt] = (f32x4){0, 0, 0, 0};
        #pragma unroll
        for (int c = 0; c < 4; ++c) {
            dma_chunk(c < 3 ? hb + 32768 + (c + 1) * 16384 : hb + 98304, bB, w, tid);
            PRIO1();
            #pragma unroll
            for (int ks = 0; ks < 8; ++ks) {
                s16x8 a;
                if (ks < 4) a = vvr[ks];
                else {
                    int byte = 8192 + ((l15 * 256 + ((ks - 4) * 32 + lg * 8) * 2) ^ ((l15 & 7) << 4));
                    a = *(const s16x8*)(myscr + byte);
                }
                #pragma unroll
                for (int ct = 0; ct < 4; ++ct)
                    m1[c * 4 + ct] = mfma16(a, B256(bA, ct, ks), m1[c * 4 + ct]);
            }
            PRIO0();
            CB();
        }
        #pragma unroll
        for (int nt = 0; nt < 16; ++nt) {   // m1g -> scratch @0 [16][256] (overlays q/k1)
            int c = nt * 16 + l15;
            float bias = lu_b[h * 256 + c];
            #pragma unroll
            for (int r = 0; r < 4; ++r) {
                float g = bf2f((short)((gpk[nt][r >> 1] >> ((r & 1) * 16)) & 0xFFFFu));
                int row = rb + r;
                int byte = (row * 512 + c * 2) ^ ((row & 7) << 4);
                *(short*)(myscr + byte) = f2bf((m1[nt][r] + bias) * g);
            }
        }

        // ---- steps 7-8: stage D, msgW chunks c=0..1 ----
        f32x4 m2[8];
        #pragma unroll
        for (int nt = 0; nt < 8; ++nt) m2[nt] = (f32x4){0, 0, 0, 0};
        #pragma unroll
        for (int c = 0; c < 2; ++c) {
            dma_chunk(c == 0 ? hb + 114688 : hb + 131072, bB, w, tid);
            PRIO1();
            #pragma unroll
            for (int ks = 0; ks < 8; ++ks) {
                int byte = (l15 * 512 + (ks * 32 + lg * 8) * 2) ^ ((l15 & 7) << 4);
                s16x8 a = *(const s16x8*)(myscr + byte);
                #pragma unroll
                for (int ct = 0; ct < 4; ++ct)
                    m2[c * 4 + ct] = mfma16(a, B256(bA, ct, ks), m2[c * 4 + ct]);
            }
            PRIO0();
            CB();
        }
        {   // LN2 + leaky -> m2 scratch @8192 (verified)
            float s[4] = {0, 0, 0, 0}, s2[4] = {0, 0, 0, 0};
            #pragma unroll
            for (int nt = 0; nt < 8; ++nt) {
                int c = nt * 16 + l15;
                float bias = msg_b[h * 128 + c];
                #pragma unroll
                for (int r = 0; r < 4; ++r) {
                    float v = m2[nt][r] + bias;
                    m2[nt][r] = v;
                    s[r] += v; s2[r] += v * v;
                }
            }
            #pragma unroll
            for (int m = 1; m < 16; m <<= 1)
                #pragma unroll
                for (int r = 0; r < 4; ++r) { s[r] += __shfl_xor(s[r], m); s2[r] += __shfl_xor(s2[r], m); }
            float mean[4], rstd[4];
            #pragma unroll
            for (int r = 0; r < 4; ++r) {
                mean[r] = s[r] * (1.f / 128.f);
                float var = s2[r] * (1.f / 128.f) - mean[r] * mean[r];
                rstd[r] = rsqrtf(var + EPSV);
            }
            #pragma unroll
            for (int nt = 0; nt < 8; ++nt) {
                int c = nt * 16 + l15;
                float g2 = ln2_g[h * 128 + c], b2 = ln2_b[h * 128 + c];
                #pragma unroll
                for (int r = 0; r < 4; ++r) {
                    float v = (m2[nt][r] - mean[r]) * rstd[r] * g2 + b2;
                    v = v > 0.f ? v : v * NEGS;
                    int row = rb + r;
                    int byte = 8192 + ((row * 256 + c * 2) ^ ((row & 7) << 4));
                    *(short*)(myscr + byte) = f2bf(v);
                }
            }
        }

        // ---- step 9: DMA KW(h+1); stage E from bA (CAT) ----
        if (h < 3) dma_chunk(imgW + (h + 1) * 147456, bB, w, tid);
        PRIO1();
        #pragma unroll
        for (int ks = 0; ks < 4; ++ks) {
            int byte = 8192 + ((l15 * 256 + (ks * 32 + lg * 8) * 2) ^ ((l15 & 7) << 4));
            s16x8 a = *(const s16x8*)(myscr + byte);
            #pragma unroll
            for (int ct = 0; ct < 8; ++ct)
                outc[ct] = mfma16(a, B128(bA, ct, ks), outc[ct]);
        }
        PRIO0();
        CB();
    }

    // ---- scatter: one 128-wide atomic add per valid edge ----
    #pragma unroll
    for (int nt = 0; nt < 8; ++nt) {
        int c = nt * 16 + l15;
        #pragma unroll
        for (int r = 0; r < 4; ++r)
            if (validC[r])
                atomicAdd(out1 + (size_t)dstC[r] * 128 + c, outc[nt][r]);
    }
}

// ---------------- BN statistics ----------------
__global__ void bn_stats(const float* __restrict__ out1, const float* __restrict__ cat_b,
                         float* __restrict__ stats)
{
    const int col = threadIdx.x;
    const int r0 = blockIdx.x * 128;
    const float cb = cat_b[col];
    float s = 0.f, s2 = 0.f;
    for (int i = 0; i < 128; ++i) {
        int row = r0 + i;
        if (row < NN) {
            float v = out1[(size_t)row * 128 + col] + cb;
            s += v; s2 += v * v;
        }
    }
    atomicAdd(stats + col, s);
    atomicAdd(stats + 128 + col, s2);
}

// ---------------- finalize: BN + leaky + residual ----------------
__global__ void finalize(const float* __restrict__ out1, const float* __restrict__ resid,
                         const float* __restrict__ stats, const float* __restrict__ cat_b,
                         const float* __restrict__ bn_g, const float* __restrict__ bn_b,
                         const float* __restrict__ inp_b, float* __restrict__ out)
{
    int i = blockIdx.x * 256 + threadIdx.x;
    if (i >= NN * 128) return;
    int col = i & 127;
    float mu = stats[col] * (1.f / NN);
    float var = stats[128 + col] * (1.f / NN) - mu * mu;
    float rstd = rsqrtf(var + EPSV);
    float v = out1[i] + cat_b[col];
    v = (v - mu) * rstd * bn_g[col] + bn_b[col];
    v = v > 0.f ? v : v * NEGS;
    out[i] = v + resid[i] + inp_b[col];
}

extern "C" void kernel_launch(void* const* d_in, const int* in_sizes, int n_in,
                              void* d_out, int out_size, void* d_ws, size_t ws_size,
                              hipStream_t stream)
{
    (void)in_sizes; (void)n_in; (void)out_size; (void)ws_size;
    const float* x     = (const float*)d_in[0];
    const int*   eidx  = (const int*)d_in[1];
    const float* ef    = (const float*)d_in[2];
    const float* Kv2v  = (const float*)d_in[3];
    const float* Ke2v  = (const float*)d_in[4];
    const float* Vv2v  = (const float*)d_in[5];
    const float* Ve2v  = (const float*)d_in[6];
    const float* lu_W  = (const float*)d_in[7];
    const float* lu_b  = (const float*)d_in[8];
    const float* ln1_g = (const float*)d_in[9];
    const float* ln1_b = (const float*)d_in[10];
    const float* msg_W = (const float*)d_in[11];
    const float* msg_b = (const float*)d_in[12];
    const float* ln2_g = (const float*)d_in[13];
    const float* ln2_b = (const float*)d_in[14];
    const float* cat_W = (const float*)d_in[15];
    const float* cat_b = (const float*)d_in[16];
    const float* inp_W = (const float*)d_in[17];
    const float* inp_b = (const float*)d_in[18];
    const float* bn_g  = (const float*)d_in[19];
    const float* bn_b  = (const float*)d_in[20];

    char* ws = (char*)d_ws;
    short* nodeW_t = (short*)(ws + 0);          // 294912
    short* imgW    = (short*)(ws + 294912);     // 1179648 (4 heads x 294912)
    short* Kv_all  = (short*)(ws + 1474560);    // 51,200,000
    short* Vv_all  = (short*)(ws + 52674560);   // 51,200,000
    float* resid   = (float*)(ws + 103874560);  // 25,600,000
    float* out1    = (float*)(ws + 129474560);  // 25,600,000
    float* stats   = (float*)(ws + 155074560);  // 1024

    hipFuncSetAttribute((const void*)edge_kernel,
                        hipFuncAttributeMaxDynamicSharedMemorySize, 163840);

    hipMemsetAsync(out1, 0, 25600000 + 1024, stream);   // out1 + stats (contiguous)
    prep_weights<<<2880, 256, 0, stream>>>(Kv2v, Vv2v, inp_W, Ke2v, Ve2v, lu_W, msg_W, cat_W,
                                           nodeW_t, imgW);
    node_proj<<<782, 256, 0, stream>>>(x, nodeW_t, Kv_all, Vv_all, resid);
    edge_kernel<<<1563, 512, 163840, stream>>>(ef, eidx, Kv_all, Vv_all, imgW,
                                               lu_b, ln1_g, ln1_b, msg_b,
                                               ln2_g, ln2_b, out1);
    bn_stats<<<391, 128, 0, stream>>>(out1, cat_b, stats);
    finalize<<<25000, 256, 0, stream>>>(out1, resid, stats, cat_b, bn_g, bn_b, inp_b,
                                        (float*)d_out);
}

// Round 8
// 2489.244 us; speedup vs baseline: 1.0106x; 1.0106x over previous
//
#include <hip/hip_runtime.h>
#include <hip/hip_bf16.h>

#define NN 50000
#define NE 200000
#define HEADS 4
#define EPSV 1e-5f
#define NEGS 0.01f

using f32x4 = __attribute__((ext_vector_type(4))) float;
using s16x8 = __attribute__((ext_vector_type(8))) short;
using bf16x8 = __attribute__((ext_vector_type(8))) __bf16;

__device__ __forceinline__ short f2bf(float f) {
    union { float f; unsigned u; } v; v.f = f;
    unsigned r = v.u + 0x7FFFu + ((v.u >> 16) & 1u);
    return (short)(r >> 16);
}
__device__ __forceinline__ float bf2f(short s) {
    union { unsigned u; float f; } v; v.u = ((unsigned)(unsigned short)s) << 16;
    return v.f;
}
__device__ __forceinline__ f32x4 mfma16(s16x8 a, s16x8 b, f32x4 c) {
    return __builtin_amdgcn_mfma_f32_16x16x32_bf16(
        __builtin_bit_cast(bf16x8, a), __builtin_bit_cast(bf16x8, b), c, 0, 0, 0);
}
__device__ __forceinline__ void gld16(const void* g, void* l) {
    __builtin_amdgcn_global_load_lds(
        (const __attribute__((address_space(1))) void*)g,
        (__attribute__((address_space(3))) void*)l, 16, 0, 0);
}
// DMA one 32KB chunk (16384 shorts) image -> LDS, all 512 threads (4 ops each)
__device__ __forceinline__ void dma_chunk(const short* src, char* dst, int w, int tid) {
    #pragma unroll
    for (int op = 0; op < 4; ++op)
        gld16(src + op * 4096 + tid * 8, dst + op * 8192 + w * 1024);
}

// ---------------- weight prep (unchanged from R6-verified) ----------------
__global__ void prep_weights(const float* __restrict__ Kv2v, const float* __restrict__ Vv2v,
                             const float* __restrict__ inpW,
                             const float* __restrict__ Ke2v, const float* __restrict__ Ve2v,
                             const float* __restrict__ luW, const float* __restrict__ msgW,
                             const float* __restrict__ catW,
                             short* __restrict__ nodeW_t, short* __restrict__ imgW)
{
    int i = blockIdx.x * 256 + threadIdx.x;
    if (i < 147456) {                       // nodeW_t [1152][128]
        int j = i >> 7, k = i & 127;
        float v;
        if (j < 512)       v = Kv2v[(j >> 7) * 16384 + k * 128 + (j & 127)];
        else if (j < 1024) v = Vv2v[((j - 512) >> 7) * 16384 + k * 128 + (j & 127)];
        else               v = inpW[k * 128 + (j - 1024)];
        nodeW_t[i] = f2bf(v);
        return;
    }
    i -= 147456;
    if (i >= 589824) return;
    int h = i / 147456;
    int r = i % 147456;
    short* img = imgW + h * 147456;
    if (r < 16384) {                        // KW (K=128)
        int colc = r >> 7, k = r & 127;
        img[(colc * 128 + k) ^ ((colc & 7) << 3)] = f2bf(Ke2v[h * 16384 + k * 128 + colc]);
    } else if (r < 32768) {                 // VW (K=128)
        int e = r - 16384; int colc = e >> 7, k = e & 127;
        img[16384 + ((colc * 128 + k) ^ ((colc & 7) << 3))] = f2bf(Ve2v[h * 16384 + k * 128 + colc]);
    } else if (r < 98304) {                 // LU (K=256, 4 chunks of 64 cols)
        int e = r - 32768; int c = e >> 14, ec = e & 16383;
        int colc = ec >> 8, k = ec & 255; int col = c * 64 + colc;
        img[32768 + c * 16384 + ((colc * 256 + k) ^ ((colc & 7) << 3))] =
            f2bf(luW[h * 65536 + k * 256 + col]);
    } else if (r < 131072) {                // MSG (K=256, 2 chunks of 64 cols)
        int e = r - 98304; int c = e >> 14, ec = e & 16383;
        int colc = ec >> 8, k = ec & 255; int col = c * 64 + colc;
        img[98304 + c * 16384 + ((colc * 256 + k) ^ ((colc & 7) << 3))] =
            f2bf(msgW[h * 32768 + k * 128 + col]);
    } else {                                // CAT (K=128)
        int e = r - 131072; int colc = e >> 7, k = e & 127;
        img[131072 + ((colc * 128 + k) ^ ((colc & 7) << 3))] =
            f2bf(catW[(h * 128 + k) * 128 + colc]);
    }
}

// ---------------- node projections (unchanged, verified) ----------------
__global__ __launch_bounds__(256, 2)
void node_proj(const float* __restrict__ x, const short* __restrict__ nodeW_t,
               short* __restrict__ Kv_all, short* __restrict__ Vv_all,
               float* __restrict__ resid)
{
    __shared__ alignas(16) short xt[64 * 128];
    const int tid = threadIdx.x;
    const int row0 = blockIdx.x * 64;
    #pragma unroll
    for (int it = 0; it < 8; ++it) {
        int idx4 = it * 256 + tid;
        int r = idx4 >> 5;
        int c = (idx4 & 31) * 4;
        float4 v = {0.f, 0.f, 0.f, 0.f};
        if (row0 + r < NN) v = *(const float4*)(x + (size_t)(row0 + r) * 128 + c);
        short4 sw; sw.x = f2bf(v.x); sw.y = f2bf(v.y); sw.z = f2bf(v.z); sw.w = f2bf(v.w);
        int byte = (r * 256 + c * 2) ^ ((r & 7) << 4);
        *(short4*)((char*)xt + byte) = sw;
    }
    __syncthreads();
    const int lane = tid & 63, w = tid >> 6;
    const int l15 = lane & 15, lg = lane >> 4;
    const int rloc = w * 16 + l15;
    s16x8 a[4];
    #pragma unroll
    for (int ks = 0; ks < 4; ++ks) {
        int byte = (rloc * 256 + (ks * 32 + lg * 8) * 2) ^ ((rloc & 7) << 4);
        a[ks] = *(const s16x8*)((const char*)xt + byte);
    }
    const int rowC = row0 + w * 16 + lg * 4;
    for (int nc = 0; nc < 18; ++nc) {
        f32x4 acc[4];
        s16x8 b[16];
        #pragma unroll
        for (int q = 0; q < 4; ++q) {
            acc[q] = (f32x4){0.f, 0.f, 0.f, 0.f};
            int j = (nc * 4 + q) * 16 + l15;
            #pragma unroll
            for (int ks = 0; ks < 4; ++ks)
                b[q * 4 + ks] = *(const s16x8*)(nodeW_t + j * 128 + ks * 32 + lg * 8);
        }
        #pragma unroll
        for (int q = 0; q < 4; ++q)
            #pragma unroll
            for (int ks = 0; ks < 4; ++ks)
                acc[q] = mfma16(a[ks], b[q * 4 + ks], acc[q]);
        #pragma unroll
        for (int q = 0; q < 4; ++q) {
            int j = (nc * 4 + q) * 16 + l15;
            #pragma unroll
            for (int r = 0; r < 4; ++r) {
                int row = rowC + r;
                if (row >= NN) continue;
                if (j < 512)       Kv_all[(size_t)row * 512 + j] = f2bf(acc[q][r]);
                else if (j < 1024) Vv_all[(size_t)row * 512 + (j - 512)] = f2bf(acc[q][r]);
                else               resid[(size_t)row * 128 + (j - 1024)] = acc[q][r];
            }
        }
    }
}

// ---------------- fused edge pipeline: 8 waves, 128 edges/block, dbuf DMA ----------------
// dynamic LDS 163840: wbuf0 @0 (32K), wbuf1 @32768 (32K),
// per-wave scratch @65536 + w*12288: q@0 [16][128], k1@4096, VE/m2@8192 [16][128],
// m1g@0 [16][256] (overlays q/k1)
#define B128(buf, ct, ks) \
    (*(const s16x8*)((const short*)(buf) + (((((ct) * 16 + l15) * 128) + (ks) * 32 + lg * 8) ^ ((l15 & 7) << 3))))
#define B256(buf, ct, ks) \
    (*(const s16x8*)((const short*)(buf) + (((((ct) * 16 + l15) * 256) + (ks) * 32 + lg * 8) ^ ((l15 & 7) << 3))))
#define CB() do { __syncthreads(); char* _t = bA; bA = bB; bB = _t; } while (0)
#define PRIO1() __builtin_amdgcn_s_setprio(1)
#define PRIO0() __builtin_amdgcn_s_setprio(0)

// launch_bounds(512, 1): empirically hipcc allocates VGPR ~= 256/arg2 —
// (512,2) gave VGPR=128 and massive spill (R7: +2.4GB HBM traffic). arg2=1
// yields the full 256-VGPR budget; an 8-wave block then fits exactly
// 2 waves/SIMD (2 x 256 = 512-reg pool), which is the occupancy we want.
__global__ __launch_bounds__(512, 1)
void edge_kernel(const float* __restrict__ ef, const int* __restrict__ eidx,
                 const short* __restrict__ Kv_all, const short* __restrict__ Vv_all,
                 const short* __restrict__ imgW,
                 const float* __restrict__ lu_b, const float* __restrict__ ln1_g,
                 const float* __restrict__ ln1_b, const float* __restrict__ msg_b,
                 const float* __restrict__ ln2_g, const float* __restrict__ ln2_b,
                 float* __restrict__ out1)
{
    extern __shared__ char lds[];
    char* bA = lds;
    char* bB = lds + 32768;
    const int tid = threadIdx.x;
    const int lane = tid & 63, w = tid >> 6;
    const int l15 = lane & 15, lg = lane >> 4;
    const int e0 = blockIdx.x * 128 + w * 16;
    const int rb = lg * 4;
    char* myscr = lds + 65536 + w * 12288;
    const float scale = 0.0625f;   // 1/sqrt(2*OUT)

    // prologue: DMA KW(h=0) into bB; ef A-fragments; indices (clamped for tail)
    dma_chunk(imgW, bB, w, tid);
    const int eA = min(e0 + l15, NE - 1);
    const float* efr = ef + (size_t)eA * 128 + lg * 8;
    s16x8 aef[4];
    #pragma unroll
    for (int ks = 0; ks < 4; ++ks) {
        float4 v0 = *(const float4*)(efr + ks * 32);
        float4 v1 = *(const float4*)(efr + ks * 32 + 4);
        s16x8 t;
        t[0] = f2bf(v0.x); t[1] = f2bf(v0.y); t[2] = f2bf(v0.z); t[3] = f2bf(v0.w);
        t[4] = f2bf(v1.x); t[5] = f2bf(v1.y); t[6] = f2bf(v1.z); t[7] = f2bf(v1.w);
        aef[ks] = t;
    }
    const int srcA = eidx[eA];
    int dstC[4], validC[4];
    #pragma unroll
    for (int r = 0; r < 4; ++r) {
        int e = e0 + rb + r;
        validC[r] = (e < NE);
        dstC[r] = eidx[NE + min(e, NE - 1)];
    }
    const int gRow = lane >> 2;            // 0..15
    const int gChunk = lane & 3;           // 0..3
    const int eG = min(e0 + gRow, NE - 1);
    const int dstG = eidx[NE + eG];
    const int srcG = eidx[eG];

    f32x4 outc[8];
    #pragma unroll
    for (int nt = 0; nt < 8; ++nt) outc[nt] = (f32x4){0.f, 0.f, 0.f, 0.f};
    CB();   // KW0 ready in bA

    for (int h = 0; h < HEADS; ++h) {
        const short* hb = imgW + h * 147456;
        // q/k1 gathers (latency hidden under step 1)
        s16x8 qv[4], kv[4];
        #pragma unroll
        for (int j = 0; j < 4; ++j) {
            qv[j] = *(const s16x8*)(Kv_all + (size_t)dstG * 512 + h * 128 + gChunk * 32 + j * 8);
            kv[j] = *(const s16x8*)(Kv_all + (size_t)srcG * 512 + h * 128 + gChunk * 32 + j * 8);
        }

        // ---- step 1: DMA VW; accK = ef@KW (bA) ----
        dma_chunk(hb + 16384, bB, w, tid);
        f32x4 accK[8];
        #pragma unroll
        for (int nt = 0; nt < 8; ++nt) accK[nt] = (f32x4){0, 0, 0, 0};
        PRIO1();
        #pragma unroll
        for (int ks = 0; ks < 4; ++ks)
            #pragma unroll
            for (int ct = 0; ct < 8; ++ct)
                accK[ct] = mfma16(aef[ks], B128(bA, ct, ks), accK[ct]);
        PRIO0();
        #pragma unroll
        for (int j = 0; j < 4; ++j) {       // q/k1 -> scratch
            int byte = gRow * 256 + ((((gChunk * 4 + j) * 16)) ^ ((gRow & 7) << 4));
            *(s16x8*)(myscr + byte) = qv[j];
            *(s16x8*)(myscr + 4096 + byte) = kv[j];
        }
        CB();

        // ---- step 2: DMA LU0; accV = ef@VW (bA); VE->scratch; LN1+gate; vvr ----
        dma_chunk(hb + 32768, bB, w, tid);
        f32x4 accV[8];
        #pragma unroll
        for (int nt = 0; nt < 8; ++nt) accV[nt] = (f32x4){0, 0, 0, 0};
        PRIO1();
        #pragma unroll
        for (int ks = 0; ks < 4; ++ks)
            #pragma unroll
            for (int ct = 0; ct < 8; ++ct)
                accV[ct] = mfma16(aef[ks], B128(bA, ct, ks), accV[ct]);
        PRIO0();
        #pragma unroll
        for (int nt = 0; nt < 8; ++nt) {    // VE -> scratch @8192 [16][128]
            int c = nt * 16 + l15;
            #pragma unroll
            for (int r = 0; r < 4; ++r) {
                int row = rb + r;
                int byte = 8192 + ((row * 256 + c * 2) ^ ((row & 7) << 4));
                *(short*)(myscr + byte) = f2bf(accV[nt][r]);
            }
        }
        s16x8 vvr[4];
        #pragma unroll
        for (int ks = 0; ks < 4; ++ks)
            vvr[ks] = *(const s16x8*)(Vv_all + (size_t)srcA * 512 + h * 128 + ks * 32 + lg * 8);
        unsigned gpk[16][2];
        #pragma unroll
        for (int r = 0; r < 4; ++r) {       // LN1 + sigmoid gate (verified)
            const int i = rb + r;
            const int swz = (i & 7) << 4;
            float al[16];
            float s = 0.f, s2 = 0.f;
            #pragma unroll
            for (int nt = 0; nt < 8; ++nt) {
                int off = (i * 256 + nt * 32 + l15 * 2) ^ swz;
                float q  = bf2f(*(const short*)(myscr + off));
                float k1 = bf2f(*(const short*)(myscr + 4096 + off));
                float alo = q * k1 * scale;
                float ahi = q * accK[nt][r] * scale;
                al[nt] = alo; al[nt + 8] = ahi;
                s += alo + ahi; s2 += alo * alo + ahi * ahi;
            }
            #pragma unroll
            for (int m = 1; m < 16; m <<= 1) { s += __shfl_xor(s, m); s2 += __shfl_xor(s2, m); }
            float mean = s * (1.f / 256.f);
            float var  = s2 * (1.f / 256.f) - mean * mean;
            float rstd = rsqrtf(var + EPSV);
            #pragma unroll
            for (int i2 = 0; i2 < 16; ++i2) {
                int c = i2 * 16 + l15;
                float z = (al[i2] - mean) * rstd * ln1_g[h * 256 + c] + ln1_b[h * 256 + c];
                float g = 1.f / (1.f + __expf(-z));
                unsigned gb = (unsigned)(unsigned short)f2bf(g);
                if ((r & 1) == 0) gpk[i2][r >> 1] = gb;
                else              gpk[i2][r >> 1] |= gb << 16;
            }
        }
        CB();

        // ---- steps 3-6: stage C, luW chunks c=0..3 (64 cols each) ----
        f32x4 m1[16];
        #pragma unroll
        for (int nt = 0; nt < 16; ++nt) m1[nt] = (f32x4){0, 0, 0, 0};
        #pragma unroll
        for (int c = 0; c < 4; ++c) {
            dma_chunk(c < 3 ? hb + 32768 + (c + 1) * 16384 : hb + 98304, bB, w, tid);
            PRIO1();
            #pragma unroll
            for (int ks = 0; ks < 8; ++ks) {
                s16x8 a;
                if (ks < 4) a = vvr[ks];
                else {
                    int byte = 8192 + ((l15 * 256 + ((ks - 4) * 32 + lg * 8) * 2) ^ ((l15 & 7) << 4));
                    a = *(const s16x8*)(myscr + byte);
                }
                #pragma unroll
                for (int ct = 0; ct < 4; ++ct)
                    m1[c * 4 + ct] = mfma16(a, B256(bA, ct, ks), m1[c * 4 + ct]);
            }
            PRIO0();
            CB();
        }
        #pragma unroll
        for (int nt = 0; nt < 16; ++nt) {   // m1g -> scratch @0 [16][256] (overlays q/k1)
            int c = nt * 16 + l15;
            float bias = lu_b[h * 256 + c];
            #pragma unroll
            for (int r = 0; r < 4; ++r) {
                float g = bf2f((short)((gpk[nt][r >> 1] >> ((r & 1) * 16)) & 0xFFFFu));
                int row = rb + r;
                int byte = (row * 512 + c * 2) ^ ((row & 7) << 4);
                *(short*)(myscr + byte) = f2bf((m1[nt][r] + bias) * g);
            }
        }

        // ---- steps 7-8: stage D, msgW chunks c=0..1 ----
        f32x4 m2[8];
        #pragma unroll
        for (int nt = 0; nt < 8; ++nt) m2[nt] = (f32x4){0, 0, 0, 0};
        #pragma unroll
        for (int c = 0; c < 2; ++c) {
            dma_chunk(c == 0 ? hb + 114688 : hb + 131072, bB, w, tid);
            PRIO1();
            #pragma unroll
            for (int ks = 0; ks < 8; ++ks) {
                int byte = (l15 * 512 + (ks * 32 + lg * 8) * 2) ^ ((l15 & 7) << 4);
                s16x8 a = *(const s16x8*)(myscr + byte);
                #pragma unroll
                for (int ct = 0; ct < 4; ++ct)
                    m2[c * 4 + ct] = mfma16(a, B256(bA, ct, ks), m2[c * 4 + ct]);
            }
            PRIO0();
            CB();
        }
        {   // LN2 + leaky -> m2 scratch @8192 (verified)
            float s[4] = {0, 0, 0, 0}, s2[4] = {0, 0, 0, 0};
            #pragma unroll
            for (int nt = 0; nt < 8; ++nt) {
                int c = nt * 16 + l15;
                float bias = msg_b[h * 128 + c];
                #pragma unroll
                for (int r = 0; r < 4; ++r) {
                    float v = m2[nt][r] + bias;
                    m2[nt][r] = v;
                    s[r] += v; s2[r] += v * v;
                }
            }
            #pragma unroll
            for (int m = 1; m < 16; m <<= 1)
                #pragma unroll
                for (int r = 0; r < 4; ++r) { s[r] += __shfl_xor(s[r], m); s2[r] += __shfl_xor(s2[r], m); }
            float mean[4], rstd[4];
            #pragma unroll
            for (int r = 0; r < 4; ++r) {
                mean[r] = s[r] * (1.f / 128.f);
                float var = s2[r] * (1.f / 128.f) - mean[r] * mean[r];
                rstd[r] = rsqrtf(var + EPSV);
            }
            #pragma unroll
            for (int nt = 0; nt < 8; ++nt) {
                int c = nt * 16 + l15;
                float g2 = ln2_g[h * 128 + c], b2 = ln2_b[h * 128 + c];
                #pragma unroll
                for (int r = 0; r < 4; ++r) {
                    float v = (m2[nt][r] - mean[r]) * rstd[r] * g2 + b2;
                    v = v > 0.f ? v : v * NEGS;
                    int row = rb + r;
                    int byte = 8192 + ((row * 256 + c * 2) ^ ((row & 7) << 4));
                    *(short*)(myscr + byte) = f2bf(v);
                }
            }
        }

        // ---- step 9: DMA KW(h+1); stage E from bA (CAT) ----
        if (h < 3) dma_chunk(imgW + (h + 1) * 147456, bB, w, tid);
        PRIO1();
        #pragma unroll
        for (int ks = 0; ks < 4; ++ks) {
            int byte = 8192 + ((l15 * 256 + (ks * 32 + lg * 8) * 2) ^ ((l15 & 7) << 4));
            s16x8 a = *(const s16x8*)(myscr + byte);
            #pragma unroll
            for (int ct = 0; ct < 8; ++ct)
                outc[ct] = mfma16(a, B128(bA, ct, ks), outc[ct]);
        }
        PRIO0();
        CB();
    }

    // ---- scatter: one 128-wide atomic add per valid edge ----
    #pragma unroll
    for (int nt = 0; nt < 8; ++nt) {
        int c = nt * 16 + l15;
        #pragma unroll
        for (int r = 0; r < 4; ++r)
            if (validC[r])
                atomicAdd(out1 + (size_t)dstC[r] * 128 + c, outc[nt][r]);
    }
}

// ---------------- BN statistics ----------------
__global__ void bn_stats(const float* __restrict__ out1, const float* __restrict__ cat_b,
                         float* __restrict__ stats)
{
    const int col = threadIdx.x;
    const int r0 = blockIdx.x * 128;
    const float cb = cat_b[col];
    float s = 0.f, s2 = 0.f;
    for (int i = 0; i < 128; ++i) {
        int row = r0 + i;
        if (row < NN) {
            float v = out1[(size_t)row * 128 + col] + cb;
            s += v; s2 += v * v;
        }
    }
    atomicAdd(stats + col, s);
    atomicAdd(stats + 128 + col, s2);
}

// ---------------- finalize: BN + leaky + residual ----------------
__global__ void finalize(const float* __restrict__ out1, const float* __restrict__ resid,
                         const float* __restrict__ stats, const float* __restrict__ cat_b,
                         const float* __restrict__ bn_g, const float* __restrict__ bn_b,
                         const float* __restrict__ inp_b, float* __restrict__ out)
{
    int i = blockIdx.x * 256 + threadIdx.x;
    if (i >= NN * 128) return;
    int col = i & 127;
    float mu = stats[col] * (1.f / NN);
    float var = stats[128 + col] * (1.f / NN) - mu * mu;
    float rstd = rsqrtf(var + EPSV);
    float v = out1[i] + cat_b[col];
    v = (v - mu) * rstd * bn_g[col] + bn_b[col];
    v = v > 0.f ? v : v * NEGS;
    out[i] = v + resid[i] + inp_b[col];
}

extern "C" void kernel_launch(void* const* d_in, const int* in_sizes, int n_in,
                              void* d_out, int out_size, void* d_ws, size_t ws_size,
                              hipStream_t stream)
{
    (void)in_sizes; (void)n_in; (void)out_size; (void)ws_size;
    const float* x     = (const float*)d_in[0];
    const int*   eidx  = (const int*)d_in[1];
    const float* ef    = (const float*)d_in[2];
    const float* Kv2v  = (const float*)d_in[3];
    const float* Ke2v  = (const float*)d_in[4];
    const float* Vv2v  = (const float*)d_in[5];
    const float* Ve2v  = (const float*)d_in[6];
    const float* lu_W  = (const float*)d_in[7];
    const float* lu_b  = (const float*)d_in[8];
    const float* ln1_g = (const float*)d_in[9];
    const float* ln1_b = (const float*)d_in[10];
    const float* msg_W = (const float*)d_in[11];
    const float* msg_b = (const float*)d_in[12];
    const float* ln2_g = (const float*)d_in[13];
    const float* ln2_b = (const float*)d_in[14];
    const float* cat_W = (const float*)d_in[15];
    const float* cat_b = (const float*)d_in[16];
    const float* inp_W = (const float*)d_in[17];
    const float* inp_b = (const float*)d_in[18];
    const float* bn_g  = (const float*)d_in[19];
    const float* bn_b  = (const float*)d_in[20];

    char* ws = (char*)d_ws;
    short* nodeW_t = (short*)(ws + 0);          // 294912
    short* imgW    = (short*)(ws + 294912);     // 1179648 (4 heads x 294912)
    short* Kv_all  = (short*)(ws + 1474560);    // 51,200,000
    short* Vv_all  = (short*)(ws + 52674560);   // 51,200,000
    float* resid   = (float*)(ws + 103874560);  // 25,600,000
    float* out1    = (float*)(ws + 129474560);  // 25,600,000
    float* stats   = (float*)(ws + 155074560);  // 1024

    hipFuncSetAttribute((const void*)edge_kernel,
                        hipFuncAttributeMaxDynamicSharedMemorySize, 163840);

    hipMemsetAsync(out1, 0, 25600000 + 1024, stream);   // out1 + stats (contiguous)
    prep_weights<<<2880, 256, 0, stream>>>(Kv2v, Vv2v, inp_W, Ke2v, Ve2v, lu_W, msg_W, cat_W,
                                           nodeW_t, imgW);
    node_proj<<<782, 256, 0, stream>>>(x, nodeW_t, Kv_all, Vv_all, resid);
    edge_kernel<<<1563, 512, 163840, stream>>>(ef, eidx, Kv_all, Vv_all, imgW,
                                               lu_b, ln1_g, ln1_b, msg_b,
                                               ln2_g, ln2_b, out1);
    bn_stats<<<391, 128, 0, stream>>>(out1, cat_b, stats);
    finalize<<<25000, 256, 0, stream>>>(out1, resid, stats, cat_b, bn_g, bn_b, inp_b,
                                        (float*)d_out);
}

// Round 9
// 1423.170 us; speedup vs baseline: 1.7677x; 1.7491x over previous
//
#include <hip/hip_runtime.h>
#include <hip/hip_bf16.h>

#define NN 50000
#define NE 200000
#define HEADS 4
#define EPSV 1e-5f
#define NEGS 0.01f

using f32x4 = __attribute__((ext_vector_type(4))) float;
using s16x8 = __attribute__((ext_vector_type(8))) short;
using bf16x8 = __attribute__((ext_vector_type(8))) __bf16;

__device__ __forceinline__ short f2bf(float f) {
    union { float f; unsigned u; } v; v.f = f;
    unsigned r = v.u + 0x7FFFu + ((v.u >> 16) & 1u);
    return (short)(r >> 16);
}
__device__ __forceinline__ float bf2f(short s) {
    union { unsigned u; float f; } v; v.u = ((unsigned)(unsigned short)s) << 16;
    return v.f;
}
__device__ __forceinline__ f32x4 mfma16(s16x8 a, s16x8 b, f32x4 c) {
    return __builtin_amdgcn_mfma_f32_16x16x32_bf16(
        __builtin_bit_cast(bf16x8, a), __builtin_bit_cast(bf16x8, b), c, 0, 0, 0);
}
__device__ __forceinline__ void gld16(const void* g, void* l) {
    __builtin_amdgcn_global_load_lds(
        (const __attribute__((address_space(1))) void*)g,
        (__attribute__((address_space(3))) void*)l, 16, 0, 0);
}
// DMA one 16KB chunk (8192 shorts) image -> LDS, 256 threads, 4 ops each
__device__ __forceinline__ void dma16(const short* src, char* dst, int w, int lane) {
    #pragma unroll
    for (int op = 0; op < 4; ++op)
        gld16(src + op * 2048 + w * 512 + lane * 8, dst + op * 4096 + w * 1024);
}

// ---------------- weight prep (unchanged from R6-verified) ----------------
// imgW per-head (shorts): KW@0 (16384), VW@16384, LU@32768 (4x16384),
// MSG@98304 (2x16384), CAT@131072. Entry (colc,k): (colc*K+k) ^ ((colc&7)<<3).
// 16KB sub-chunks are contiguous halves of each 32KB block (64 cols of K=128
// or 32 cols of K=256) with identical intra-offsets.
__global__ void prep_weights(const float* __restrict__ Kv2v, const float* __restrict__ Vv2v,
                             const float* __restrict__ inpW,
                             const float* __restrict__ Ke2v, const float* __restrict__ Ve2v,
                             const float* __restrict__ luW, const float* __restrict__ msgW,
                             const float* __restrict__ catW,
                             short* __restrict__ nodeW_t, short* __restrict__ imgW)
{
    int i = blockIdx.x * 256 + threadIdx.x;
    if (i < 147456) {                       // nodeW_t [1152][128]
        int j = i >> 7, k = i & 127;
        float v;
        if (j < 512)       v = Kv2v[(j >> 7) * 16384 + k * 128 + (j & 127)];
        else if (j < 1024) v = Vv2v[((j - 512) >> 7) * 16384 + k * 128 + (j & 127)];
        else               v = inpW[k * 128 + (j - 1024)];
        nodeW_t[i] = f2bf(v);
        return;
    }
    i -= 147456;
    if (i >= 589824) return;
    int h = i / 147456;
    int r = i % 147456;
    short* img = imgW + h * 147456;
    if (r < 16384) {                        // KW (K=128)
        int colc = r >> 7, k = r & 127;
        img[(colc * 128 + k) ^ ((colc & 7) << 3)] = f2bf(Ke2v[h * 16384 + k * 128 + colc]);
    } else if (r < 32768) {                 // VW (K=128)
        int e = r - 16384; int colc = e >> 7, k = e & 127;
        img[16384 + ((colc * 128 + k) ^ ((colc & 7) << 3))] = f2bf(Ve2v[h * 16384 + k * 128 + colc]);
    } else if (r < 98304) {                 // LU (K=256, 4 blocks of 64 cols)
        int e = r - 32768; int c = e >> 14, ec = e & 16383;
        int colc = ec >> 8, k = ec & 255; int col = c * 64 + colc;
        img[32768 + c * 16384 + ((colc * 256 + k) ^ ((colc & 7) << 3))] =
            f2bf(luW[h * 65536 + k * 256 + col]);
    } else if (r < 131072) {                // MSG (K=256, 2 blocks of 64 cols)
        int e = r - 98304; int c = e >> 14, ec = e & 16383;
        int colc = ec >> 8, k = ec & 255; int col = c * 64 + colc;
        img[98304 + c * 16384 + ((colc * 256 + k) ^ ((colc & 7) << 3))] =
            f2bf(msgW[h * 32768 + k * 128 + col]);
    } else {                                // CAT (K=128)
        int e = r - 131072; int colc = e >> 7, k = e & 127;
        img[131072 + ((colc * 128 + k) ^ ((colc & 7) << 3))] =
            f2bf(catW[(h * 128 + k) * 128 + colc]);
    }
}

// ---------------- node projections (unchanged, verified) ----------------
__global__ __launch_bounds__(256, 2)
void node_proj(const float* __restrict__ x, const short* __restrict__ nodeW_t,
               short* __restrict__ Kv_all, short* __restrict__ Vv_all,
               float* __restrict__ resid)
{
    __shared__ alignas(16) short xt[64 * 128];
    const int tid = threadIdx.x;
    const int row0 = blockIdx.x * 64;
    #pragma unroll
    for (int it = 0; it < 8; ++it) {
        int idx4 = it * 256 + tid;
        int r = idx4 >> 5;
        int c = (idx4 & 31) * 4;
        float4 v = {0.f, 0.f, 0.f, 0.f};
        if (row0 + r < NN) v = *(const float4*)(x + (size_t)(row0 + r) * 128 + c);
        short4 sw; sw.x = f2bf(v.x); sw.y = f2bf(v.y); sw.z = f2bf(v.z); sw.w = f2bf(v.w);
        int byte = (r * 256 + c * 2) ^ ((r & 7) << 4);
        *(short4*)((char*)xt + byte) = sw;
    }
    __syncthreads();
    const int lane = tid & 63, w = tid >> 6;
    const int l15 = lane & 15, lg = lane >> 4;
    const int rloc = w * 16 + l15;
    s16x8 a[4];
    #pragma unroll
    for (int ks = 0; ks < 4; ++ks) {
        int byte = (rloc * 256 + (ks * 32 + lg * 8) * 2) ^ ((rloc & 7) << 4);
        a[ks] = *(const s16x8*)((const char*)xt + byte);
    }
    const int rowC = row0 + w * 16 + lg * 4;
    for (int nc = 0; nc < 18; ++nc) {
        f32x4 acc[4];
        s16x8 b[16];
        #pragma unroll
        for (int q = 0; q < 4; ++q) {
            acc[q] = (f32x4){0.f, 0.f, 0.f, 0.f};
            int j = (nc * 4 + q) * 16 + l15;
            #pragma unroll
            for (int ks = 0; ks < 4; ++ks)
                b[q * 4 + ks] = *(const s16x8*)(nodeW_t + j * 128 + ks * 32 + lg * 8);
        }
        #pragma unroll
        for (int q = 0; q < 4; ++q)
            #pragma unroll
            for (int ks = 0; ks < 4; ++ks)
                acc[q] = mfma16(a[ks], b[q * 4 + ks], acc[q]);
        #pragma unroll
        for (int q = 0; q < 4; ++q) {
            int j = (nc * 4 + q) * 16 + l15;
            #pragma unroll
            for (int r = 0; r < 4; ++r) {
                int row = rowC + r;
                if (row >= NN) continue;
                if (j < 512)       Kv_all[(size_t)row * 512 + j] = f2bf(acc[q][r]);
                else if (j < 1024) Vv_all[(size_t)row * 512 + (j - 512)] = f2bf(acc[q][r]);
                else               resid[(size_t)row * 128 + (j - 1024)] = acc[q][r];
            }
        }
    }
}

// ---------------- fused edge pipeline: 4 waves, 64 edges/block, 80KB LDS ----------------
// dynamic LDS 81920: wbuf0 @0 (16K), wbuf1 @16384 (16K),
// per-wave scratch @32768 + w*12288: q@0 [16][128], k1@4096, VE/m2@8192 [16][128],
// m1g@0 [16][256] (overlays q/k1).
// 2 blocks/CU (2x80KB LDS = 160KB; 8 waves x 256 VGPR = 2048 pool) -> 2 waves/SIMD.
#define B128h(buf, ct, ks) \
    (*(const s16x8*)((const short*)(buf) + (((((ct) * 16 + l15) * 128) + (ks) * 32 + lg * 8) ^ ((l15 & 7) << 3))))
#define B256h(buf, ct, ks) \
    (*(const s16x8*)((const short*)(buf) + (((((ct) * 16 + l15) * 256) + (ks) * 32 + lg * 8) ^ ((l15 & 7) << 3))))
#define CB() do { __syncthreads(); char* _t = bA; bA = bB; bB = _t; } while (0)
#define PRIO1() __builtin_amdgcn_s_setprio(1)
#define PRIO0() __builtin_amdgcn_s_setprio(0)

__global__ __launch_bounds__(256, 1)
void edge_kernel(const float* __restrict__ ef, const int* __restrict__ eidx,
                 const short* __restrict__ Kv_all, const short* __restrict__ Vv_all,
                 const short* __restrict__ imgW,
                 const float* __restrict__ lu_b, const float* __restrict__ ln1_g,
                 const float* __restrict__ ln1_b, const float* __restrict__ msg_b,
                 const float* __restrict__ ln2_g, const float* __restrict__ ln2_b,
                 float* __restrict__ out1)
{
    extern __shared__ char lds[];
    char* bA = lds;
    char* bB = lds + 16384;
    const int tid = threadIdx.x;
    const int lane = tid & 63, w = tid >> 6;
    const int l15 = lane & 15, lg = lane >> 4;
    const int e0 = blockIdx.x * 64 + w * 16;
    const int rb = lg * 4;
    char* myscr = lds + 32768 + w * 12288;
    const float scale = 0.0625f;   // 1/sqrt(2*OUT)

    // prologue: DMA KW0(h=0); ef A-fragments; indices
    dma16(imgW, bB, w, lane);
    const float* efr = ef + (size_t)(e0 + l15) * 128 + lg * 8;
    s16x8 aef[4];
    #pragma unroll
    for (int ks = 0; ks < 4; ++ks) {
        float4 v0 = *(const float4*)(efr + ks * 32);
        float4 v1 = *(const float4*)(efr + ks * 32 + 4);
        s16x8 t;
        t[0] = f2bf(v0.x); t[1] = f2bf(v0.y); t[2] = f2bf(v0.z); t[3] = f2bf(v0.w);
        t[4] = f2bf(v1.x); t[5] = f2bf(v1.y); t[6] = f2bf(v1.z); t[7] = f2bf(v1.w);
        aef[ks] = t;
    }
    const int srcA = eidx[e0 + l15];
    int dstC[4];
    #pragma unroll
    for (int r = 0; r < 4; ++r) dstC[r] = eidx[NE + e0 + rb + r];
    const int gRow = lane >> 2;            // 0..15
    const int gChunk = lane & 3;           // 0..3
    const int dstG = eidx[NE + e0 + gRow];
    const int srcG = eidx[e0 + gRow];

    f32x4 outc[8];
    #pragma unroll
    for (int nt = 0; nt < 8; ++nt) outc[nt] = (f32x4){0.f, 0.f, 0.f, 0.f};
    CB();   // KW0 ready in bA

    for (int h = 0; h < HEADS; ++h) {
        const short* hb = imgW + h * 147456;
        // q/k1 gathers (latency hidden under steps 0-1)
        s16x8 qv[4], kv[4];
        #pragma unroll
        for (int j = 0; j < 4; ++j) {
            qv[j] = *(const s16x8*)(Kv_all + (size_t)dstG * 512 + h * 128 + gChunk * 32 + j * 8);
            kv[j] = *(const s16x8*)(Kv_all + (size_t)srcG * 512 + h * 128 + gChunk * 32 + j * 8);
        }

        f32x4 accK[8], accV[8];
        #pragma unroll
        for (int nt = 0; nt < 8; ++nt) { accK[nt] = (f32x4){0,0,0,0}; accV[nt] = (f32x4){0,0,0,0}; }

        // ---- i0: bA=KW0 -> accK[0..3]; DMA KW1; q/k1 -> scratch ----
        dma16(hb + 8192, bB, w, lane);
        PRIO1();
        #pragma unroll
        for (int ks = 0; ks < 4; ++ks)
            #pragma unroll
            for (int ct = 0; ct < 4; ++ct)
                accK[ct] = mfma16(aef[ks], B128h(bA, ct, ks), accK[ct]);
        PRIO0();
        #pragma unroll
        for (int j = 0; j < 4; ++j) {
            int byte = gRow * 256 + ((((gChunk * 4 + j) * 16)) ^ ((gRow & 7) << 4));
            *(s16x8*)(myscr + byte) = qv[j];
            *(s16x8*)(myscr + 4096 + byte) = kv[j];
        }
        CB();

        // ---- i1: bA=KW1 -> accK[4..7]; DMA VW0 ----
        dma16(hb + 16384, bB, w, lane);
        PRIO1();
        #pragma unroll
        for (int ks = 0; ks < 4; ++ks)
            #pragma unroll
            for (int ct = 0; ct < 4; ++ct)
                accK[4 + ct] = mfma16(aef[ks], B128h(bA, ct, ks), accK[4 + ct]);
        PRIO0();
        CB();

        // ---- i2: bA=VW0 -> accV[0..3]; DMA VW1 ----
        dma16(hb + 24576, bB, w, lane);
        PRIO1();
        #pragma unroll
        for (int ks = 0; ks < 4; ++ks)
            #pragma unroll
            for (int ct = 0; ct < 4; ++ct)
                accV[ct] = mfma16(aef[ks], B128h(bA, ct, ks), accV[ct]);
        PRIO0();
        CB();

        // ---- i3: bA=VW1 -> accV[4..7]; DMA LU0; VE->scratch; vvr; LN1+gate ----
        dma16(hb + 32768, bB, w, lane);
        PRIO1();
        #pragma unroll
        for (int ks = 0; ks < 4; ++ks)
            #pragma unroll
            for (int ct = 0; ct < 4; ++ct)
                accV[4 + ct] = mfma16(aef[ks], B128h(bA, ct, ks), accV[4 + ct]);
        PRIO0();
        #pragma unroll
        for (int nt = 0; nt < 8; ++nt) {    // VE -> scratch @8192 [16][128]
            int c = nt * 16 + l15;
            #pragma unroll
            for (int r = 0; r < 4; ++r) {
                int row = rb + r;
                int byte = 8192 + ((row * 256 + c * 2) ^ ((row & 7) << 4));
                *(short*)(myscr + byte) = f2bf(accV[nt][r]);
            }
        }
        s16x8 vvr[4];
        #pragma unroll
        for (int ks = 0; ks < 4; ++ks)
            vvr[ks] = *(const s16x8*)(Vv_all + (size_t)srcA * 512 + h * 128 + ks * 32 + lg * 8);
        unsigned gpk[16][2];
        #pragma unroll
        for (int r = 0; r < 4; ++r) {       // LN1 + sigmoid gate (verified)
            const int i = rb + r;
            const int swz = (i & 7) << 4;
            float al[16];
            float s = 0.f, s2 = 0.f;
            #pragma unroll
            for (int nt = 0; nt < 8; ++nt) {
                int off = (i * 256 + nt * 32 + l15 * 2) ^ swz;
                float q  = bf2f(*(const short*)(myscr + off));
                float k1 = bf2f(*(const short*)(myscr + 4096 + off));
                float alo = q * k1 * scale;
                float ahi = q * accK[nt][r] * scale;
                al[nt] = alo; al[nt + 8] = ahi;
                s += alo + ahi; s2 += alo * alo + ahi * ahi;
            }
            #pragma unroll
            for (int m = 1; m < 16; m <<= 1) { s += __shfl_xor(s, m); s2 += __shfl_xor(s2, m); }
            float mean = s * (1.f / 256.f);
            float var  = s2 * (1.f / 256.f) - mean * mean;
            float rstd = rsqrtf(var + EPSV);
            #pragma unroll
            for (int i2 = 0; i2 < 16; ++i2) {
                int c = i2 * 16 + l15;
                float z = (al[i2] - mean) * rstd * ln1_g[h * 256 + c] + ln1_b[h * 256 + c];
                float g = 1.f / (1.f + __expf(-z));
                unsigned gb = (unsigned)(unsigned short)f2bf(g);
                if ((r & 1) == 0) gpk[i2][r >> 1] = gb;
                else              gpk[i2][r >> 1] |= gb << 16;
            }
        }
        CB();

        // ---- i4..i11: LU chunks 0..7 (32 cols each) ----
        f32x4 m1[16];
        #pragma unroll
        for (int nt = 0; nt < 16; ++nt) m1[nt] = (f32x4){0, 0, 0, 0};
        #pragma unroll
        for (int c = 0; c < 8; ++c) {
            dma16(c < 7 ? hb + 32768 + (c + 1) * 8192 : hb + 98304, bB, w, lane);
            PRIO1();
            #pragma unroll
            for (int ks = 0; ks < 8; ++ks) {
                s16x8 a;
                if (ks < 4) a = vvr[ks];
                else {
                    int byte = 8192 + ((l15 * 256 + ((ks - 4) * 32 + lg * 8) * 2) ^ ((l15 & 7) << 4));
                    a = *(const s16x8*)(myscr + byte);
                }
                m1[c * 2]     = mfma16(a, B256h(bA, 0, ks), m1[c * 2]);
                m1[c * 2 + 1] = mfma16(a, B256h(bA, 1, ks), m1[c * 2 + 1]);
            }
            PRIO0();
            CB();
        }
        #pragma unroll
        for (int nt = 0; nt < 16; ++nt) {   // m1g -> scratch @0 [16][256] (overlays q/k1)
            int c = nt * 16 + l15;
            float bias = lu_b[h * 256 + c];
            #pragma unroll
            for (int r = 0; r < 4; ++r) {
                float g = bf2f((short)((gpk[nt][r >> 1] >> ((r & 1) * 16)) & 0xFFFFu));
                int row = rb + r;
                int byte = (row * 512 + c * 2) ^ ((row & 7) << 4);
                *(short*)(myscr + byte) = f2bf((m1[nt][r] + bias) * g);
            }
        }

        // ---- i12..i15: MSG chunks 0..3 (32 cols each) ----
        f32x4 m2[8];
        #pragma unroll
        for (int nt = 0; nt < 8; ++nt) m2[nt] = (f32x4){0, 0, 0, 0};
        #pragma unroll
        for (int c = 0; c < 4; ++c) {
            dma16(c < 3 ? hb + 98304 + (c + 1) * 8192 : hb + 131072, bB, w, lane);
            PRIO1();
            #pragma unroll
            for (int ks = 0; ks < 8; ++ks) {
                int byte = (l15 * 512 + (ks * 32 + lg * 8) * 2) ^ ((l15 & 7) << 4);
                s16x8 a = *(const s16x8*)(myscr + byte);
                m2[c * 2]     = mfma16(a, B256h(bA, 0, ks), m2[c * 2]);
                m2[c * 2 + 1] = mfma16(a, B256h(bA, 1, ks), m2[c * 2 + 1]);
            }
            PRIO0();
            CB();
        }
        {   // LN2 + leaky -> m2 scratch @8192 (verified)
            float s[4] = {0, 0, 0, 0}, s2[4] = {0, 0, 0, 0};
            #pragma unroll
            for (int nt = 0; nt < 8; ++nt) {
                int c = nt * 16 + l15;
                float bias = msg_b[h * 128 + c];
                #pragma unroll
                for (int r = 0; r < 4; ++r) {
                    float v = m2[nt][r] + bias;
                    m2[nt][r] = v;
                    s[r] += v; s2[r] += v * v;
                }
            }
            #pragma unroll
            for (int m = 1; m < 16; m <<= 1)
                #pragma unroll
                for (int r = 0; r < 4; ++r) { s[r] += __shfl_xor(s[r], m); s2[r] += __shfl_xor(s2[r], m); }
            float mean[4], rstd[4];
            #pragma unroll
            for (int r = 0; r < 4; ++r) {
                mean[r] = s[r] * (1.f / 128.f);
                float var = s2[r] * (1.f / 128.f) - mean[r] * mean[r];
                rstd[r] = rsqrtf(var + EPSV);
            }
            #pragma unroll
            for (int nt = 0; nt < 8; ++nt) {
                int c = nt * 16 + l15;
                float g2 = ln2_g[h * 128 + c], b2 = ln2_b[h * 128 + c];
                #pragma unroll
                for (int r = 0; r < 4; ++r) {
                    float v = (m2[nt][r] - mean[r]) * rstd[r] * g2 + b2;
                    v = v > 0.f ? v : v * NEGS;
                    int row = rb + r;
                    int byte = 8192 + ((row * 256 + c * 2) ^ ((row & 7) << 4));
                    *(short*)(myscr + byte) = f2bf(v);
                }
            }
        }

        // ---- i16: bA=CAT0 -> outc[0..3]; DMA CAT1 ----
        dma16(hb + 139264, bB, w, lane);
        PRIO1();
        #pragma unroll
        for (int ks = 0; ks < 4; ++ks) {
            int byte = 8192 + ((l15 * 256 + (ks * 32 + lg * 8) * 2) ^ ((l15 & 7) << 4));
            s16x8 a = *(const s16x8*)(myscr + byte);
            #pragma unroll
            for (int ct = 0; ct < 4; ++ct)
                outc[ct] = mfma16(a, B128h(bA, ct, ks), outc[ct]);
        }
        PRIO0();
        CB();

        // ---- i17: bA=CAT1 -> outc[4..7]; DMA next head's KW0 ----
        if (h < 3) dma16(imgW + (h + 1) * 147456, bB, w, lane);
        PRIO1();
        #pragma unroll
        for (int ks = 0; ks < 4; ++ks) {
            int byte = 8192 + ((l15 * 256 + (ks * 32 + lg * 8) * 2) ^ ((l15 & 7) << 4));
            s16x8 a = *(const s16x8*)(myscr + byte);
            #pragma unroll
            for (int ct = 0; ct < 4; ++ct)
                outc[4 + ct] = mfma16(a, B128h(bA, ct, ks), outc[4 + ct]);
        }
        PRIO0();
        CB();
    }

    // ---- scatter: one 128-wide atomic add per edge ----
    #pragma unroll
    for (int nt = 0; nt < 8; ++nt) {
        int c = nt * 16 + l15;
        #pragma unroll
        for (int r = 0; r < 4; ++r)
            atomicAdd(out1 + (size_t)dstC[r] * 128 + c, outc[nt][r]);
    }
}

// ---------------- BN statistics ----------------
__global__ void bn_stats(const float* __restrict__ out1, const float* __restrict__ cat_b,
                         float* __restrict__ stats)
{
    const int col = threadIdx.x;
    const int r0 = blockIdx.x * 128;
    const float cb = cat_b[col];
    float s = 0.f, s2 = 0.f;
    for (int i = 0; i < 128; ++i) {
        int row = r0 + i;
        if (row < NN) {
            float v = out1[(size_t)row * 128 + col] + cb;
            s += v; s2 += v * v;
        }
    }
    atomicAdd(stats + col, s);
    atomicAdd(stats + 128 + col, s2);
}

// ---------------- finalize: BN + leaky + residual ----------------
__global__ void finalize(const float* __restrict__ out1, const float* __restrict__ resid,
                         const float* __restrict__ stats, const float* __restrict__ cat_b,
                         const float* __restrict__ bn_g, const float* __restrict__ bn_b,
                         const float* __restrict__ inp_b, float* __restrict__ out)
{
    int i = blockIdx.x * 256 + threadIdx.x;
    if (i >= NN * 128) return;
    int col = i & 127;
    float mu = stats[col] * (1.f / NN);
    float var = stats[128 + col] * (1.f / NN) - mu * mu;
    float rstd = rsqrtf(var + EPSV);
    float v = out1[i] + cat_b[col];
    v = (v - mu) * rstd * bn_g[col] + bn_b[col];
    v = v > 0.f ? v : v * NEGS;
    out[i] = v + resid[i] + inp_b[col];
}

extern "C" void kernel_launch(void* const* d_in, const int* in_sizes, int n_in,
                              void* d_out, int out_size, void* d_ws, size_t ws_size,
                              hipStream_t stream)
{
    (void)in_sizes; (void)n_in; (void)out_size; (void)ws_size;
    const float* x     = (const float*)d_in[0];
    const int*   eidx  = (const int*)d_in[1];
    const float* ef    = (const float*)d_in[2];
    const float* Kv2v  = (const float*)d_in[3];
    const float* Ke2v  = (const float*)d_in[4];
    const float* Vv2v  = (const float*)d_in[5];
    const float* Ve2v  = (const float*)d_in[6];
    const float* lu_W  = (const float*)d_in[7];
    const float* lu_b  = (const float*)d_in[8];
    const float* ln1_g = (const float*)d_in[9];
    const float* ln1_b = (const float*)d_in[10];
    const float* msg_W = (const float*)d_in[11];
    const float* msg_b = (const float*)d_in[12];
    const float* ln2_g = (const float*)d_in[13];
    const float* ln2_b = (const float*)d_in[14];
    const float* cat_W = (const float*)d_in[15];
    const float* cat_b = (const float*)d_in[16];
    const float* inp_W = (const float*)d_in[17];
    const float* inp_b = (const float*)d_in[18];
    const float* bn_g  = (const float*)d_in[19];
    const float* bn_b  = (const float*)d_in[20];

    char* ws = (char*)d_ws;
    short* nodeW_t = (short*)(ws + 0);          // 294912
    short* imgW    = (short*)(ws + 294912);     // 1179648 (4 heads x 294912)
    short* Kv_all  = (short*)(ws + 1474560);    // 51,200,000
    short* Vv_all  = (short*)(ws + 52674560);   // 51,200,000
    float* resid   = (float*)(ws + 103874560);  // 25,600,000
    float* out1    = (float*)(ws + 129474560);  // 25,600,000
    float* stats   = (float*)(ws + 155074560);  // 1024

    hipFuncSetAttribute((const void*)edge_kernel,
                        hipFuncAttributeMaxDynamicSharedMemorySize, 81920);

    hipMemsetAsync(out1, 0, 25600000 + 1024, stream);   // out1 + stats (contiguous)
    prep_weights<<<2880, 256, 0, stream>>>(Kv2v, Vv2v, inp_W, Ke2v, Ve2v, lu_W, msg_W, cat_W,
                                           nodeW_t, imgW);
    node_proj<<<782, 256, 0, stream>>>(x, nodeW_t, Kv_all, Vv_all, resid);
    edge_kernel<<<3125, 256, 81920, stream>>>(ef, eidx, Kv_all, Vv_all, imgW,
                                              lu_b, ln1_g, ln1_b, msg_b,
                                              ln2_g, ln2_b, out1);
    bn_stats<<<391, 128, 0, stream>>>(out1, cat_b, stats);
    finalize<<<25000, 256, 0, stream>>>(out1, resid, stats, cat_b, bn_g, bn_b, inp_b,
                                        (float*)d_out);
}